// Round 1
// baseline (1628.477 us; speedup 1.0000x reference)
//
#include <hip/hip_runtime.h>
#include <hip/hip_bf16.h>

#define N_NODES 100000
#define N_EDGES 3200000
#define ET (N_EDGES + N_NODES)   // edges + self loops
#define F_IN 500
#define H1 8
#define C1 8
#define F1 64                    // H1*C1
#define C2 7

// ---------------- CSR build ----------------
__global__ void count_kernel(const int* __restrict__ ei, int* __restrict__ cnt) {
    int i = blockIdx.x * blockDim.x + threadIdx.x;
    if (i >= ET) return;
    int dst = (i < N_EDGES) ? ei[N_EDGES + i] : (i - N_EDGES);
    atomicAdd(&cnt[dst], 1);
}

__global__ void scan_kernel(int* __restrict__ cnt_cursor, int* __restrict__ rowptr) {
    __shared__ int sdata[1024];
    const int t = threadIdx.x;
    const int chunk = (N_NODES + 1023) / 1024;   // 98
    int start = t * chunk;
    int end = min(start + chunk, N_NODES);
    if (start > N_NODES) start = N_NODES;
    int local = 0;
    for (int i = start; i < end; ++i) local += cnt_cursor[i];
    sdata[t] = local;
    __syncthreads();
    for (int off = 1; off < 1024; off <<= 1) {
        int v = (t >= off) ? sdata[t - off] : 0;
        __syncthreads();
        sdata[t] += v;
        __syncthreads();
    }
    int run = sdata[t] - local;   // exclusive prefix of this thread's chunk
    for (int i = start; i < end; ++i) {
        int c = cnt_cursor[i];
        rowptr[i] = run;
        cnt_cursor[i] = run;      // becomes the scatter cursor
        run += c;
    }
    if (t == 1023) rowptr[N_NODES] = sdata[1023];
}

__global__ void fill_kernel(const int* __restrict__ ei, int* __restrict__ cursor,
                            int* __restrict__ col) {
    int i = blockIdx.x * blockDim.x + threadIdx.x;
    if (i >= ET) return;
    int src, dst;
    if (i < N_EDGES) { src = ei[i]; dst = ei[N_EDGES + i]; }
    else             { src = dst = i - N_EDGES; }
    int pos = atomicAdd(&cursor[dst], 1);
    col[pos] = src;
}

// ---------------- layer 1 GEMM + attention coefficients ----------------
// block = 256 threads = 4 waves; each wave computes 16 rows x 64 cols
__global__ __launch_bounds__(256) void gemm1_kernel(
    const float* __restrict__ x, const float* __restrict__ W1,
    const float* __restrict__ a_src, const float* __restrict__ a_dst,
    float* __restrict__ h1, float* __restrict__ as1, float* __restrict__ ad1)
{
    const int lane = threadIdx.x & 63;
    const int wave = threadIdx.x >> 6;
    const int row0 = blockIdx.x * 64 + wave * 16;

    float acc[16];
#pragma unroll
    for (int i = 0; i < 16; ++i) acc[i] = 0.f;

    const float* xp[16];
#pragma unroll
    for (int i = 0; i < 16; ++i) {
        int r = row0 + i;
        if (r > N_NODES - 1) r = N_NODES - 1;   // clamp: loads stay valid
        xp[i] = x + (size_t)r * F_IN;
    }

    for (int k = 0; k < F_IN; k += 4) {
        float w0 = W1[(k + 0) * F1 + lane];
        float w1 = W1[(k + 1) * F1 + lane];
        float w2 = W1[(k + 2) * F1 + lane];
        float w3 = W1[(k + 3) * F1 + lane];
#pragma unroll
        for (int i = 0; i < 16; ++i) {
            float4 xv = *(const float4*)(xp[i] + k);
            acc[i] = fmaf(xv.x, w0, acc[i]);
            acc[i] = fmaf(xv.y, w1, acc[i]);
            acc[i] = fmaf(xv.z, w2, acc[i]);
            acc[i] = fmaf(xv.w, w3, acc[i]);
        }
    }

    const float asc = a_src[lane];   // flat [h*8+c] == lane
    const float adc = a_dst[lane];
#pragma unroll
    for (int i = 0; i < 16; ++i) {
        int r = row0 + i;
        float ps = acc[i] * asc;
        float pd = acc[i] * adc;
#pragma unroll
        for (int m = 1; m < 8; m <<= 1) {
            ps += __shfl_xor(ps, m, 8);
            pd += __shfl_xor(pd, m, 8);
        }
        if (r < N_NODES) {
            h1[(size_t)r * F1 + lane] = acc[i];
            if ((lane & 7) == 0) {
                as1[r * H1 + (lane >> 3)] = ps;
                ad1[r * H1 + (lane >> 3)] = pd;
            }
        }
    }
}

// ---------------- layer 1 aggregation: thread per (node, head) ----------------
__global__ void agg1_kernel(const int* __restrict__ rowptr, const int* __restrict__ col,
                            const float* __restrict__ h1, const float* __restrict__ as1,
                            const float* __restrict__ ad1, const float* __restrict__ b1,
                            float* __restrict__ hout)
{
    int tid = blockIdx.x * blockDim.x + threadIdx.x;
    if (tid >= N_NODES * H1) return;
    const int h = tid & 7;
    const int n = tid >> 3;
    const int r0 = rowptr[n], r1 = rowptr[n + 1];
    const float adh = ad1[n * H1 + h];

    float m = -1e30f;
    for (int j = r0; j < r1; ++j) {
        int s = col[j];
        float e = as1[s * H1 + h] + adh;
        e = (e > 0.f) ? e : 0.2f * e;
        m = fmaxf(m, e);
    }
    float denom = 0.f;
    float a0 = 0, a1 = 0, a2 = 0, a3 = 0, a4 = 0, a5 = 0, a6 = 0, a7 = 0;
    for (int j = r0; j < r1; ++j) {
        int s = col[j];
        float e = as1[s * H1 + h] + adh;
        e = (e > 0.f) ? e : 0.2f * e;
        float ex = __expf(e - m);
        denom += ex;
        const float4* hp = (const float4*)(h1 + (size_t)s * F1 + h * 8);
        float4 va = hp[0];
        float4 vb = hp[1];
        a0 = fmaf(ex, va.x, a0); a1 = fmaf(ex, va.y, a1);
        a2 = fmaf(ex, va.z, a2); a3 = fmaf(ex, va.w, a3);
        a4 = fmaf(ex, vb.x, a4); a5 = fmaf(ex, vb.y, a5);
        a6 = fmaf(ex, vb.z, a6); a7 = fmaf(ex, vb.w, a7);
    }
    const float inv = 1.f / denom;
    const int base = n * F1 + h * 8;
    const int bb = h * 8;
    hout[base + 0] = a0 * inv + b1[bb + 0];
    hout[base + 1] = a1 * inv + b1[bb + 1];
    hout[base + 2] = a2 * inv + b1[bb + 2];
    hout[base + 3] = a3 * inv + b1[bb + 3];
    hout[base + 4] = a4 * inv + b1[bb + 4];
    hout[base + 5] = a5 * inv + b1[bb + 5];
    hout[base + 6] = a6 * inv + b1[bb + 6];
    hout[base + 7] = a7 * inv + b1[bb + 7];
}

// ---------------- layer 2 GEMM + attention coefficients ----------------
__global__ void gemm2_kernel(const float* __restrict__ hin, const float* __restrict__ W2,
                             const float* __restrict__ a_src, const float* __restrict__ a_dst,
                             float* __restrict__ h2, float* __restrict__ as2,
                             float* __restrict__ ad2)
{
    __shared__ float w2s[F1 * C2];
    __shared__ float as_s[C2], ad_s[C2];
    for (int i = threadIdx.x; i < F1 * C2; i += blockDim.x) w2s[i] = W2[i];
    if (threadIdx.x < C2) { as_s[threadIdx.x] = a_src[threadIdx.x]; ad_s[threadIdx.x] = a_dst[threadIdx.x]; }
    __syncthreads();

    int n = blockIdx.x * blockDim.x + threadIdx.x;
    if (n >= N_NODES) return;
    float acc[C2];
#pragma unroll
    for (int c = 0; c < C2; ++c) acc[c] = 0.f;
    const float* hp = hin + (size_t)n * F1;
    for (int k = 0; k < F1; k += 4) {
        float4 hv = *(const float4*)(hp + k);
#pragma unroll
        for (int c = 0; c < C2; ++c) {
            acc[c] = fmaf(hv.x, w2s[(k + 0) * C2 + c], acc[c]);
            acc[c] = fmaf(hv.y, w2s[(k + 1) * C2 + c], acc[c]);
            acc[c] = fmaf(hv.z, w2s[(k + 2) * C2 + c], acc[c]);
            acc[c] = fmaf(hv.w, w2s[(k + 3) * C2 + c], acc[c]);
        }
    }
    float s = 0.f, d = 0.f;
#pragma unroll
    for (int c = 0; c < C2; ++c) {
        h2[n * C2 + c] = acc[c];
        s = fmaf(acc[c], as_s[c], s);
        d = fmaf(acc[c], ad_s[c], d);
    }
    as2[n] = s;
    ad2[n] = d;
}

// ---------------- layer 2 aggregation + bias + log_softmax ----------------
__global__ void agg2_kernel(const int* __restrict__ rowptr, const int* __restrict__ col,
                            const float* __restrict__ h2, const float* __restrict__ as2,
                            const float* __restrict__ ad2, const float* __restrict__ b2,
                            float* __restrict__ out)
{
    int n = blockIdx.x * blockDim.x + threadIdx.x;
    if (n >= N_NODES) return;
    const int r0 = rowptr[n], r1 = rowptr[n + 1];
    const float adn = ad2[n];

    float m = -1e30f;
    for (int j = r0; j < r1; ++j) {
        float e = as2[col[j]] + adn;
        e = (e > 0.f) ? e : 0.2f * e;
        m = fmaxf(m, e);
    }
    float denom = 0.f;
    float acc[C2];
#pragma unroll
    for (int c = 0; c < C2; ++c) acc[c] = 0.f;
    for (int j = r0; j < r1; ++j) {
        int s = col[j];
        float e = as2[s] + adn;
        e = (e > 0.f) ? e : 0.2f * e;
        float ex = __expf(e - m);
        denom += ex;
        const float* hp = h2 + s * C2;
#pragma unroll
        for (int c = 0; c < C2; ++c) acc[c] = fmaf(ex, hp[c], acc[c]);
    }
    const float inv = 1.f / denom;
    float v[C2];
    float mx = -1e30f;
#pragma unroll
    for (int c = 0; c < C2; ++c) {
        v[c] = acc[c] * inv + b2[c];
        mx = fmaxf(mx, v[c]);
    }
    float se = 0.f;
#pragma unroll
    for (int c = 0; c < C2; ++c) se += __expf(v[c] - mx);
    const float lse = __logf(se);
#pragma unroll
    for (int c = 0; c < C2; ++c) out[n * C2 + c] = v[c] - mx - lse;
}

extern "C" void kernel_launch(void* const* d_in, const int* in_sizes, int n_in,
                              void* d_out, int out_size, void* d_ws, size_t ws_size,
                              hipStream_t stream) {
    const float* x      = (const float*)d_in[0];
    const int*   ei     = (const int*)  d_in[1];
    const float* W1     = (const float*)d_in[2];
    const float* a_src1 = (const float*)d_in[3];
    const float* a_dst1 = (const float*)d_in[4];
    const float* b1     = (const float*)d_in[5];
    const float* W2     = (const float*)d_in[6];
    const float* a_src2 = (const float*)d_in[7];
    const float* a_dst2 = (const float*)d_in[8];
    const float* b2     = (const float*)d_in[9];
    float* out = (float*)d_out;

    char* ws = (char*)d_ws;
    size_t off = 0;
    auto alloc = [&](size_t bytes) -> void* {
        void* p = ws + off;
        off += (bytes + 255) & ~(size_t)255;
        return p;
    };
    int*   rowptr = (int*)  alloc((N_NODES + 1) * sizeof(int));
    int*   cursor = (int*)  alloc((size_t)N_NODES * sizeof(int));
    int*   colidx = (int*)  alloc((size_t)ET * sizeof(int));
    float* h1     = (float*)alloc((size_t)N_NODES * F1 * sizeof(float));
    float* as1    = (float*)alloc((size_t)N_NODES * H1 * sizeof(float));
    float* ad1    = (float*)alloc((size_t)N_NODES * H1 * sizeof(float));
    float* hout1  = (float*)alloc((size_t)N_NODES * F1 * sizeof(float));
    float* h2     = (float*)alloc((size_t)N_NODES * C2 * sizeof(float));
    float* as2    = (float*)alloc((size_t)N_NODES * sizeof(float));
    float* ad2    = (float*)alloc((size_t)N_NODES * sizeof(float));

    hipMemsetAsync(cursor, 0, (size_t)N_NODES * sizeof(int), stream);
    count_kernel<<<(ET + 255) / 256, 256, 0, stream>>>(ei, cursor);
    scan_kernel<<<1, 1024, 0, stream>>>(cursor, rowptr);
    fill_kernel<<<(ET + 255) / 256, 256, 0, stream>>>(ei, cursor, colidx);
    gemm1_kernel<<<(N_NODES + 63) / 64, 256, 0, stream>>>(x, W1, a_src1, a_dst1, h1, as1, ad1);
    agg1_kernel<<<(N_NODES * H1 + 255) / 256, 256, 0, stream>>>(rowptr, colidx, h1, as1, ad1, b1, hout1);
    gemm2_kernel<<<(N_NODES + 255) / 256, 256, 0, stream>>>(hout1, W2, a_src2, a_dst2, h2, as2, ad2);
    agg2_kernel<<<(N_NODES + 255) / 256, 256, 0, stream>>>(rowptr, colidx, h2, as2, ad2, b2, out);
}

// Round 2
// 1250.535 us; speedup vs baseline: 1.3022x; 1.3022x over previous
//
#include <hip/hip_runtime.h>
#include <hip/hip_bf16.h>

#define N_NODES 100000
#define N_EDGES 3200000
#define ET (N_EDGES + N_NODES)   // edges + self loops
#define F_IN 500
#define H1 8
#define C1 8
#define F1 64                    // H1*C1
#define C2 7

// ---------------- CSR build ----------------
__global__ void count_kernel(const int* __restrict__ ei, int* __restrict__ cnt) {
    int i = blockIdx.x * blockDim.x + threadIdx.x;
    if (i >= ET) return;
    int dst = (i < N_EDGES) ? ei[N_EDGES + i] : (i - N_EDGES);
    atomicAdd(&cnt[dst], 1);
}

__global__ void scan_kernel(int* __restrict__ cnt_cursor, int* __restrict__ rowptr) {
    __shared__ int sdata[1024];
    const int t = threadIdx.x;
    const int chunk = (N_NODES + 1023) / 1024;   // 98
    int start = t * chunk;
    int end = min(start + chunk, N_NODES);
    if (start > N_NODES) start = N_NODES;
    int local = 0;
    for (int i = start; i < end; ++i) local += cnt_cursor[i];
    sdata[t] = local;
    __syncthreads();
    for (int off = 1; off < 1024; off <<= 1) {
        int v = (t >= off) ? sdata[t - off] : 0;
        __syncthreads();
        sdata[t] += v;
        __syncthreads();
    }
    int run = sdata[t] - local;   // exclusive prefix of this thread's chunk
    for (int i = start; i < end; ++i) {
        int c = cnt_cursor[i];
        rowptr[i] = run;
        cnt_cursor[i] = run;      // becomes the scatter cursor
        run += c;
    }
    if (t == 1023) rowptr[N_NODES] = sdata[1023];
}

__global__ void fill_kernel(const int* __restrict__ ei, int* __restrict__ cursor,
                            int* __restrict__ col) {
    int i = blockIdx.x * blockDim.x + threadIdx.x;
    if (i >= ET) return;
    int src, dst;
    if (i < N_EDGES) { src = ei[i]; dst = ei[N_EDGES + i]; }
    else             { src = dst = i - N_EDGES; }
    int pos = atomicAdd(&cursor[dst], 1);
    col[pos] = src;
}

// ---------------- layer 1 GEMM + attention coefficients ----------------
// block = 256 threads; 32 rows staged in LDS; wave w computes rows w*8..w*8+7,
// lane = output column (0..63). 100000 % 32 == 0, no tail handling needed.
#define G1_ROWS 32
__global__ __launch_bounds__(256) void gemm1_kernel(
    const float* __restrict__ x, const float* __restrict__ W1,
    const float* __restrict__ a_src, const float* __restrict__ a_dst,
    float* __restrict__ h1, float* __restrict__ as1, float* __restrict__ ad1)
{
    __shared__ float xs[G1_ROWS][F_IN];      // 64000 B
    const int tid  = threadIdx.x;
    const int lane = tid & 63;
    const int wave = tid >> 6;
    const int row0 = blockIdx.x * G1_ROWS;

    // flat coalesced copy: global rows are contiguous, LDS layout identical
    {
        const float4* __restrict__ xg = (const float4*)(x + (size_t)row0 * F_IN);
        float4* xls = (float4*)&xs[0][0];
        for (int idx = tid; idx < G1_ROWS * (F_IN / 4); idx += 256)
            xls[idx] = xg[idx];
    }
    __syncthreads();

    float acc[8];
#pragma unroll
    for (int r = 0; r < 8; ++r) acc[r] = 0.f;
    const int rbase = wave * 8;

    for (int k4 = 0; k4 < F_IN / 4; ++k4) {
        const int k = k4 * 4;
        const float w0 = W1[(k + 0) * F1 + lane];
        const float w1 = W1[(k + 1) * F1 + lane];
        const float w2 = W1[(k + 2) * F1 + lane];
        const float w3 = W1[(k + 3) * F1 + lane];
#pragma unroll
        for (int r = 0; r < 8; ++r) {
            const float4 xv = *(const float4*)&xs[rbase + r][k];
            acc[r] = fmaf(xv.x, w0, acc[r]);
            acc[r] = fmaf(xv.y, w1, acc[r]);
            acc[r] = fmaf(xv.z, w2, acc[r]);
            acc[r] = fmaf(xv.w, w3, acc[r]);
        }
    }

    const float asc = a_src[lane];   // flat [h*8+c] == lane
    const float adc = a_dst[lane];
#pragma unroll
    for (int r = 0; r < 8; ++r) {
        const int gr = row0 + rbase + r;
        float ps = acc[r] * asc;
        float pd = acc[r] * adc;
#pragma unroll
        for (int m = 1; m < 8; m <<= 1) {
            ps += __shfl_xor(ps, m, 8);
            pd += __shfl_xor(pd, m, 8);
        }
        h1[(size_t)gr * F1 + lane] = acc[r];
        if ((lane & 7) == 0) {
            as1[gr * H1 + (lane >> 3)] = ps;
            ad1[gr * H1 + (lane >> 3)] = pd;
        }
    }
}

// ---------------- layer 1 aggregation: wave per node, online softmax -------
// lane = h*8 + c. Per edge: uniform col load, 32B as1 row, 256B h1 row.
__global__ __launch_bounds__(256) void agg1_kernel(
    const int* __restrict__ rowptr, const int* __restrict__ col,
    const float* __restrict__ h1, const float* __restrict__ as1,
    const float* __restrict__ ad1, const float* __restrict__ b1,
    float* __restrict__ hout)
{
    const int lane = threadIdx.x & 63;
    const int n = (blockIdx.x * 256 + threadIdx.x) >> 6;   // global wave id
    if (n >= N_NODES) return;
    const int h = lane >> 3;
    const int r0 = rowptr[n], r1 = rowptr[n + 1];
    const float adh = ad1[n * H1 + h];

    float m = -1e30f, denom = 0.f, acc = 0.f;
    for (int j = r0; j < r1; ++j) {
        const int s = col[j];                              // wave-uniform
        float e = as1[s * H1 + h] + adh;
        e = (e > 0.f) ? e : 0.2f * e;
        const float hv = h1[(size_t)s * F1 + lane];
        if (e > m) {
            const float sc = __expf(m - e);                // first iter: exp(-inf)=0
            denom *= sc;
            acc *= sc;
            m = e;
        }
        const float ex = __expf(e - m);
        denom += ex;
        acc = fmaf(ex, hv, acc);
    }
    hout[(size_t)n * F1 + lane] = acc / denom + b1[lane];
}

// ---------------- layer 2 GEMM + attention coefficients ----------------
// h2 padded to stride 8 for float4 gathers in agg2.
__global__ __launch_bounds__(256) void gemm2_kernel(
    const float* __restrict__ hin, const float* __restrict__ W2,
    const float* __restrict__ a_src, const float* __restrict__ a_dst,
    float* __restrict__ h2p, float* __restrict__ as2, float* __restrict__ ad2)
{
    __shared__ float w2s[F1 * C2];
    __shared__ float as_s[C2], ad_s[C2];
    for (int i = threadIdx.x; i < F1 * C2; i += blockDim.x) w2s[i] = W2[i];
    if (threadIdx.x < C2) { as_s[threadIdx.x] = a_src[threadIdx.x]; ad_s[threadIdx.x] = a_dst[threadIdx.x]; }
    __syncthreads();

    int n = blockIdx.x * blockDim.x + threadIdx.x;
    if (n >= N_NODES) return;
    float acc[C2];
#pragma unroll
    for (int c = 0; c < C2; ++c) acc[c] = 0.f;
    const float* hp = hin + (size_t)n * F1;
    for (int k = 0; k < F1; k += 4) {
        const float4 hv = *(const float4*)(hp + k);
#pragma unroll
        for (int c = 0; c < C2; ++c) {
            acc[c] = fmaf(hv.x, w2s[(k + 0) * C2 + c], acc[c]);
            acc[c] = fmaf(hv.y, w2s[(k + 1) * C2 + c], acc[c]);
            acc[c] = fmaf(hv.z, w2s[(k + 2) * C2 + c], acc[c]);
            acc[c] = fmaf(hv.w, w2s[(k + 3) * C2 + c], acc[c]);
        }
    }
    float s = 0.f, d = 0.f;
#pragma unroll
    for (int c = 0; c < C2; ++c) {
        s = fmaf(acc[c], as_s[c], s);
        d = fmaf(acc[c], ad_s[c], d);
    }
    float4* o = (float4*)(h2p + (size_t)n * 8);
    o[0] = make_float4(acc[0], acc[1], acc[2], acc[3]);
    o[1] = make_float4(acc[4], acc[5], acc[6], 0.f);
    as2[n] = s;
    ad2[n] = d;
}

// ---------------- layer 2 aggregation + bias + log_softmax ----------------
__global__ __launch_bounds__(256) void agg2_kernel(
    const int* __restrict__ rowptr, const int* __restrict__ col,
    const float* __restrict__ h2p, const float* __restrict__ as2,
    const float* __restrict__ ad2, const float* __restrict__ b2,
    float* __restrict__ out)
{
    int n = blockIdx.x * blockDim.x + threadIdx.x;
    if (n >= N_NODES) return;
    const int r0 = rowptr[n], r1 = rowptr[n + 1];
    const float adn = ad2[n];

    float m = -1e30f, denom = 0.f;
    float a0 = 0, a1 = 0, a2 = 0, a3 = 0, a4 = 0, a5 = 0, a6 = 0;
    for (int j = r0; j < r1; ++j) {
        const int s = col[j];
        float e = as2[s] + adn;
        e = (e > 0.f) ? e : 0.2f * e;
        const float4 va = *(const float4*)(h2p + (size_t)s * 8);
        const float4 vb = *(const float4*)(h2p + (size_t)s * 8 + 4);
        if (e > m) {
            const float sc = __expf(m - e);
            denom *= sc;
            a0 *= sc; a1 *= sc; a2 *= sc; a3 *= sc; a4 *= sc; a5 *= sc; a6 *= sc;
            m = e;
        }
        const float ex = __expf(e - m);
        denom += ex;
        a0 = fmaf(ex, va.x, a0); a1 = fmaf(ex, va.y, a1);
        a2 = fmaf(ex, va.z, a2); a3 = fmaf(ex, va.w, a3);
        a4 = fmaf(ex, vb.x, a4); a5 = fmaf(ex, vb.y, a5);
        a6 = fmaf(ex, vb.z, a6);
    }
    const float inv = 1.f / denom;
    float v[C2];
    v[0] = a0 * inv + b2[0]; v[1] = a1 * inv + b2[1];
    v[2] = a2 * inv + b2[2]; v[3] = a3 * inv + b2[3];
    v[4] = a4 * inv + b2[4]; v[5] = a5 * inv + b2[5];
    v[6] = a6 * inv + b2[6];
    float mx = -1e30f;
#pragma unroll
    for (int c = 0; c < C2; ++c) mx = fmaxf(mx, v[c]);
    float se = 0.f;
#pragma unroll
    for (int c = 0; c < C2; ++c) se += __expf(v[c] - mx);
    const float lse = __logf(se);
#pragma unroll
    for (int c = 0; c < C2; ++c) out[n * C2 + c] = v[c] - mx - lse;
}

extern "C" void kernel_launch(void* const* d_in, const int* in_sizes, int n_in,
                              void* d_out, int out_size, void* d_ws, size_t ws_size,
                              hipStream_t stream) {
    const float* x      = (const float*)d_in[0];
    const int*   ei     = (const int*)  d_in[1];
    const float* W1     = (const float*)d_in[2];
    const float* a_src1 = (const float*)d_in[3];
    const float* a_dst1 = (const float*)d_in[4];
    const float* b1     = (const float*)d_in[5];
    const float* W2     = (const float*)d_in[6];
    const float* a_src2 = (const float*)d_in[7];
    const float* a_dst2 = (const float*)d_in[8];
    const float* b2     = (const float*)d_in[9];
    float* out = (float*)d_out;

    char* ws = (char*)d_ws;
    size_t off = 0;
    auto alloc = [&](size_t bytes) -> void* {
        void* p = ws + off;
        off += (bytes + 255) & ~(size_t)255;
        return p;
    };
    int*   rowptr = (int*)  alloc((N_NODES + 1) * sizeof(int));
    int*   cursor = (int*)  alloc((size_t)N_NODES * sizeof(int));
    int*   colidx = (int*)  alloc((size_t)ET * sizeof(int));
    float* h1     = (float*)alloc((size_t)N_NODES * F1 * sizeof(float));
    float* as1    = (float*)alloc((size_t)N_NODES * H1 * sizeof(float));
    float* ad1    = (float*)alloc((size_t)N_NODES * H1 * sizeof(float));
    float* hout1  = (float*)alloc((size_t)N_NODES * F1 * sizeof(float));
    float* h2p    = (float*)alloc((size_t)N_NODES * 8 * sizeof(float));
    float* as2    = (float*)alloc((size_t)N_NODES * sizeof(float));
    float* ad2    = (float*)alloc((size_t)N_NODES * sizeof(float));

    hipMemsetAsync(cursor, 0, (size_t)N_NODES * sizeof(int), stream);
    count_kernel<<<(ET + 255) / 256, 256, 0, stream>>>(ei, cursor);
    scan_kernel<<<1, 1024, 0, stream>>>(cursor, rowptr);
    fill_kernel<<<(ET + 255) / 256, 256, 0, stream>>>(ei, cursor, colidx);
    gemm1_kernel<<<N_NODES / G1_ROWS, 256, 0, stream>>>(x, W1, a_src1, a_dst1, h1, as1, ad1);
    agg1_kernel<<<(N_NODES + 3) / 4, 256, 0, stream>>>(rowptr, colidx, h1, as1, ad1, b1, hout1);
    gemm2_kernel<<<(N_NODES + 255) / 256, 256, 0, stream>>>(hout1, W2, a_src2, a_dst2, h2p, as2, ad2);
    agg2_kernel<<<(N_NODES + 255) / 256, 256, 0, stream>>>(rowptr, colidx, h2p, as2, ad2, b2, out);
}

// Round 3
// 914.507 us; speedup vs baseline: 1.7807x; 1.3674x over previous
//
#include <hip/hip_runtime.h>
#include <hip/hip_bf16.h>

#define N_NODES 100000
#define N_EDGES 3200000
#define ET (N_EDGES + N_NODES)   // edges + self loops
#define F_IN 500
#define H1 8
#define C1 8
#define F1 64                    // H1*C1
#define C2 7

// ---------------- CSR build ----------------
__global__ void count_kernel(const int* __restrict__ ei, int* __restrict__ cnt) {
    int i = blockIdx.x * blockDim.x + threadIdx.x;
    if (i >= ET) return;
    int dst = (i < N_EDGES) ? ei[N_EDGES + i] : (i - N_EDGES);
    atomicAdd(&cnt[dst], 1);
}

// single block, 1024 threads, tiled coalesced block-scan
__global__ __launch_bounds__(1024) void scan_kernel(int* __restrict__ cnt_cursor,
                                                    int* __restrict__ rowptr) {
    __shared__ int wsum[16];
    const int t = threadIdx.x;
    const int lane = t & 63;
    const int w = t >> 6;
    int running = 0;
    const int NT = ((N_NODES + 1023) / 1024) * 1024;    // 100352
    for (int t0 = 0; t0 < NT; t0 += 1024) {
        const int i = t0 + t;
        const int v = (i < N_NODES) ? cnt_cursor[i] : 0;
        // inclusive wave scan
        int sc = v;
#pragma unroll
        for (int d = 1; d < 64; d <<= 1) {
            int u = __shfl_up(sc, d);
            if (lane >= d) sc += u;
        }
        if (lane == 63) wsum[w] = sc;
        __syncthreads();
        if (t < 16) {
            int ws = wsum[t];
#pragma unroll
            for (int d = 1; d < 16; d <<= 1) {
                int u = __shfl_up(ws, d);
                if (t >= d) ws += u;
            }
            wsum[t] = ws;
        }
        __syncthreads();
        const int base = running + (w ? wsum[w - 1] : 0);
        if (i < N_NODES) {
            const int excl = base + sc - v;
            rowptr[i] = excl;
            cnt_cursor[i] = excl;    // becomes the scatter cursor
        }
        const int tot = wsum[15];
        __syncthreads();
        running += tot;
    }
    if (t == 0) rowptr[N_NODES] = running;
}

__global__ void fill_kernel(const int* __restrict__ ei, int* __restrict__ cursor,
                            int* __restrict__ col) {
    int i = blockIdx.x * blockDim.x + threadIdx.x;
    if (i >= ET) return;
    int src, dst;
    if (i < N_EDGES) { src = ei[i]; dst = ei[N_EDGES + i]; }
    else             { src = dst = i - N_EDGES; }
    int pos = atomicAdd(&cursor[dst], 1);
    col[pos] = src;
}

// ---------------- layer 1 GEMM + attention coefficients ----------------
// block = 256 (4 waves); 32 rows; K chunked by 100 -> LDS 12.8 KB -> high occupancy.
#define G1_ROWS 32
#define KC 100
__global__ __launch_bounds__(256) void gemm1_kernel(
    const float* __restrict__ x, const float* __restrict__ W1,
    const float* __restrict__ a_src, const float* __restrict__ a_dst,
    float* __restrict__ h1, float* __restrict__ as1, float* __restrict__ ad1)
{
    __shared__ float xs[G1_ROWS][KC];        // 12800 B
    const int tid  = threadIdx.x;
    const int lane = tid & 63;
    const int wave = tid >> 6;
    const int row0 = blockIdx.x * G1_ROWS;   // 100000 % 32 == 0
    const int rbase = wave * 8;

    float acc[8];
#pragma unroll
    for (int r = 0; r < 8; ++r) acc[r] = 0.f;

    const int crow = tid >> 3;               // copy: row, 8 threads per row
    const int cq   = tid & 7;

    for (int c = 0; c < 5; ++c) {
        if (c) __syncthreads();
        {   // stage x[row0..row0+31][c*100 .. c*100+99] into LDS
            const float4* src = (const float4*)(x + (size_t)(row0 + crow) * F_IN + c * KC);
            float4* dst = (float4*)&xs[crow][0];
            dst[cq]      = src[cq];
            dst[cq + 8]  = src[cq + 8];
            dst[cq + 16] = src[cq + 16];
            if (cq == 0) dst[24] = src[24];
        }
        __syncthreads();

        const float* wp = W1 + (c * KC) * F1 + lane;
#pragma unroll 5
        for (int k4 = 0; k4 < KC / 4; ++k4) {
            const float w0 = wp[0];
            const float w1 = wp[F1];
            const float w2 = wp[2 * F1];
            const float w3 = wp[3 * F1];
            wp += 4 * F1;
#pragma unroll
            for (int r = 0; r < 8; ++r) {
                const float4 xv = *(const float4*)&xs[rbase + r][k4 * 4];
                acc[r] = fmaf(xv.x, w0, acc[r]);
                acc[r] = fmaf(xv.y, w1, acc[r]);
                acc[r] = fmaf(xv.z, w2, acc[r]);
                acc[r] = fmaf(xv.w, w3, acc[r]);
            }
        }
    }

    const float asc = a_src[lane];   // flat [h*8+c] == lane
    const float adc = a_dst[lane];
#pragma unroll
    for (int r = 0; r < 8; ++r) {
        const int gr = row0 + rbase + r;
        float ps = acc[r] * asc;
        float pd = acc[r] * adc;
#pragma unroll
        for (int m = 1; m < 8; m <<= 1) {
            ps += __shfl_xor(ps, m, 8);
            pd += __shfl_xor(pd, m, 8);
        }
        h1[(size_t)gr * F1 + lane] = acc[r];
        if ((lane & 7) == 0) {
            as1[gr * H1 + (lane >> 3)] = ps;
            ad1[gr * H1 + (lane >> 3)] = pd;
        }
    }
}

// ---------------- layer 1 aggregation: wave per node ----------------
// branch-free online softmax, 4-edge unroll. lane = h*8 + c.
__global__ __launch_bounds__(256) void agg1_kernel(
    const int* __restrict__ rowptr, const int* __restrict__ col,
    const float* __restrict__ h1, const float* __restrict__ as1,
    const float* __restrict__ ad1, const float* __restrict__ b1,
    float* __restrict__ hout)
{
    const int lane = threadIdx.x & 63;
    const int n = (blockIdx.x << 2) + (threadIdx.x >> 6);
    if (n >= N_NODES) return;
    const int h = lane >> 3;
    const int r0 = rowptr[n], r1 = rowptr[n + 1];
    const float adh = ad1[(n << 3) + h];

    float m = -1e30f, denom = 0.f, acc = 0.f;
    int j = r0;
    for (; j + 4 <= r1; j += 4) {
        const int s0 = col[j], s1 = col[j + 1], s2 = col[j + 2], s3 = col[j + 3];
        const float f0 = as1[(s0 << 3) + h], f1 = as1[(s1 << 3) + h];
        const float f2 = as1[(s2 << 3) + h], f3 = as1[(s3 << 3) + h];
        const float v0 = h1[(s0 << 6) + lane], v1 = h1[(s1 << 6) + lane];
        const float v2 = h1[(s2 << 6) + lane], v3 = h1[(s3 << 6) + lane];
        float e0 = f0 + adh; e0 = fmaxf(e0, 0.2f * e0);
        float e1 = f1 + adh; e1 = fmaxf(e1, 0.2f * e1);
        float e2 = f2 + adh; e2 = fmaxf(e2, 0.2f * e2);
        float e3 = f3 + adh; e3 = fmaxf(e3, 0.2f * e3);
        const float nm = fmaxf(fmaxf(m, fmaxf(e0, e1)), fmaxf(e2, e3));
        const float sc = __expf(m - nm);
        const float p0 = __expf(e0 - nm), p1 = __expf(e1 - nm);
        const float p2 = __expf(e2 - nm), p3 = __expf(e3 - nm);
        denom = fmaf(denom, sc, (p0 + p1) + (p2 + p3));
        acc *= sc;
        acc = fmaf(p0, v0, acc);
        acc = fmaf(p1, v1, acc);
        acc = fmaf(p2, v2, acc);
        acc = fmaf(p3, v3, acc);
        m = nm;
    }
    for (; j < r1; ++j) {
        const int s = col[j];
        float e = as1[(s << 3) + h] + adh;
        e = fmaxf(e, 0.2f * e);
        const float v = h1[(s << 6) + lane];
        const float nm = fmaxf(m, e);
        const float sc = __expf(m - nm);
        const float p = __expf(e - nm);
        denom = fmaf(denom, sc, p);
        acc = fmaf(p, v, acc * sc);
        m = nm;
    }
    hout[(n << 6) + lane] = acc / denom + b1[lane];
}

// ---------------- layer 2 GEMM + attention coefficients ----------------
__global__ __launch_bounds__(256) void gemm2_kernel(
    const float* __restrict__ hin, const float* __restrict__ W2,
    const float* __restrict__ a_src, const float* __restrict__ a_dst,
    float* __restrict__ h2p, float* __restrict__ as2, float* __restrict__ ad2)
{
    __shared__ float w2s[F1 * C2];
    __shared__ float as_s[C2], ad_s[C2];
    for (int i = threadIdx.x; i < F1 * C2; i += blockDim.x) w2s[i] = W2[i];
    if (threadIdx.x < C2) { as_s[threadIdx.x] = a_src[threadIdx.x]; ad_s[threadIdx.x] = a_dst[threadIdx.x]; }
    __syncthreads();

    int n = blockIdx.x * blockDim.x + threadIdx.x;
    if (n >= N_NODES) return;
    float acc[C2];
#pragma unroll
    for (int c = 0; c < C2; ++c) acc[c] = 0.f;
    const float* hp = hin + (size_t)n * F1;
    for (int k = 0; k < F1; k += 4) {
        const float4 hv = *(const float4*)(hp + k);
#pragma unroll
        for (int c = 0; c < C2; ++c) {
            acc[c] = fmaf(hv.x, w2s[(k + 0) * C2 + c], acc[c]);
            acc[c] = fmaf(hv.y, w2s[(k + 1) * C2 + c], acc[c]);
            acc[c] = fmaf(hv.z, w2s[(k + 2) * C2 + c], acc[c]);
            acc[c] = fmaf(hv.w, w2s[(k + 3) * C2 + c], acc[c]);
        }
    }
    float s = 0.f, d = 0.f;
#pragma unroll
    for (int c = 0; c < C2; ++c) {
        s = fmaf(acc[c], as_s[c], s);
        d = fmaf(acc[c], ad_s[c], d);
    }
    float4* o = (float4*)(h2p + (size_t)n * 8);
    o[0] = make_float4(acc[0], acc[1], acc[2], acc[3]);
    o[1] = make_float4(acc[4], acc[5], acc[6], 0.f);
    as2[n] = s;
    ad2[n] = d;
}

// ---------------- layer 2 aggregation + bias + log_softmax ----------------
// quarter-wave (4 lanes) per node; online-softmax state merge via shfl_xor.
__global__ __launch_bounds__(256) void agg2_kernel(
    const int* __restrict__ rowptr, const int* __restrict__ col,
    const float* __restrict__ h2p, const float* __restrict__ as2,
    const float* __restrict__ ad2, const float* __restrict__ b2,
    float* __restrict__ out)
{
    const int gq = (blockIdx.x * 256 + threadIdx.x) >> 2;   // node
    const int q = threadIdx.x & 3;
    if (gq >= N_NODES) return;
    const int r0 = rowptr[gq], r1 = rowptr[gq + 1];
    const float adn = ad2[gq];

    float m = -1e30f, denom = 0.f;
    float a0 = 0, a1 = 0, a2 = 0, a3 = 0, a4 = 0, a5 = 0, a6 = 0;
    for (int j = r0 + q; j < r1; j += 4) {
        const int s = col[j];
        float e = as2[s] + adn;
        e = fmaxf(e, 0.2f * e);
        const float4 va = *(const float4*)(h2p + (size_t)s * 8);
        const float4 vb = *(const float4*)(h2p + (size_t)s * 8 + 4);
        const float nm = fmaxf(m, e);
        const float sc = __expf(m - nm);
        const float ex = __expf(e - nm);
        denom = fmaf(denom, sc, ex);
        a0 = fmaf(ex, va.x, a0 * sc); a1 = fmaf(ex, va.y, a1 * sc);
        a2 = fmaf(ex, va.z, a2 * sc); a3 = fmaf(ex, va.w, a3 * sc);
        a4 = fmaf(ex, vb.x, a4 * sc); a5 = fmaf(ex, vb.y, a5 * sc);
        a6 = fmaf(ex, vb.z, a6 * sc);
        m = nm;
    }
    // merge the 4 partial states
#pragma unroll
    for (int d = 1; d < 4; d <<= 1) {
        const float om = __shfl_xor(m, d);
        const float od = __shfl_xor(denom, d);
        const float o0 = __shfl_xor(a0, d), o1 = __shfl_xor(a1, d);
        const float o2 = __shfl_xor(a2, d), o3 = __shfl_xor(a3, d);
        const float o4 = __shfl_xor(a4, d), o5 = __shfl_xor(a5, d);
        const float o6 = __shfl_xor(a6, d);
        const float nm = fmaxf(m, om);
        const float s1 = __expf(m - nm);
        const float s2 = __expf(om - nm);
        denom = denom * s1 + od * s2;
        a0 = a0 * s1 + o0 * s2; a1 = a1 * s1 + o1 * s2;
        a2 = a2 * s1 + o2 * s2; a3 = a3 * s1 + o3 * s2;
        a4 = a4 * s1 + o4 * s2; a5 = a5 * s1 + o5 * s2;
        a6 = a6 * s1 + o6 * s2;
        m = nm;
    }
    const float inv = 1.f / denom;
    float v0 = a0 * inv + b2[0], v1 = a1 * inv + b2[1];
    float v2 = a2 * inv + b2[2], v3 = a3 * inv + b2[3];
    float v4 = a4 * inv + b2[4], v5 = a5 * inv + b2[5];
    float v6 = a6 * inv + b2[6];
    float mx = fmaxf(fmaxf(fmaxf(v0, v1), fmaxf(v2, v3)), fmaxf(fmaxf(v4, v5), v6));
    const float se = __expf(v0 - mx) + __expf(v1 - mx) + __expf(v2 - mx) +
                     __expf(v3 - mx) + __expf(v4 - mx) + __expf(v5 - mx) +
                     __expf(v6 - mx);
    const float lse = __logf(se) + mx;
    // lane q writes components q and q+4 (if < 7)
    const float wa = (q == 0) ? v0 : (q == 1) ? v1 : (q == 2) ? v2 : v3;
    const float wb = (q == 0) ? v4 : (q == 1) ? v5 : v6;
    out[gq * C2 + q] = wa - lse;
    if (q < 3) out[gq * C2 + q + 4] = wb - lse;
}

extern "C" void kernel_launch(void* const* d_in, const int* in_sizes, int n_in,
                              void* d_out, int out_size, void* d_ws, size_t ws_size,
                              hipStream_t stream) {
    const float* x      = (const float*)d_in[0];
    const int*   ei     = (const int*)  d_in[1];
    const float* W1     = (const float*)d_in[2];
    const float* a_src1 = (const float*)d_in[3];
    const float* a_dst1 = (const float*)d_in[4];
    const float* b1     = (const float*)d_in[5];
    const float* W2     = (const float*)d_in[6];
    const float* a_src2 = (const float*)d_in[7];
    const float* a_dst2 = (const float*)d_in[8];
    const float* b2     = (const float*)d_in[9];
    float* out = (float*)d_out;

    char* ws = (char*)d_ws;
    size_t off = 0;
    auto alloc = [&](size_t bytes) -> void* {
        void* p = ws + off;
        off += (bytes + 255) & ~(size_t)255;
        return p;
    };
    int*   rowptr = (int*)  alloc((N_NODES + 1) * sizeof(int));
    int*   cursor = (int*)  alloc((size_t)N_NODES * sizeof(int));
    int*   colidx = (int*)  alloc((size_t)ET * sizeof(int));
    float* h1     = (float*)alloc((size_t)N_NODES * F1 * sizeof(float));
    float* as1    = (float*)alloc((size_t)N_NODES * H1 * sizeof(float));
    float* ad1    = (float*)alloc((size_t)N_NODES * H1 * sizeof(float));
    float* hout1  = (float*)alloc((size_t)N_NODES * F1 * sizeof(float));
    float* h2p    = (float*)alloc((size_t)N_NODES * 8 * sizeof(float));
    float* as2    = (float*)alloc((size_t)N_NODES * sizeof(float));
    float* ad2    = (float*)alloc((size_t)N_NODES * sizeof(float));

    hipMemsetAsync(cursor, 0, (size_t)N_NODES * sizeof(int), stream);
    count_kernel<<<(ET + 255) / 256, 256, 0, stream>>>(ei, cursor);
    scan_kernel<<<1, 1024, 0, stream>>>(cursor, rowptr);
    fill_kernel<<<(ET + 255) / 256, 256, 0, stream>>>(ei, cursor, colidx);
    gemm1_kernel<<<N_NODES / G1_ROWS, 256, 0, stream>>>(x, W1, a_src1, a_dst1, h1, as1, ad1);
    agg1_kernel<<<(N_NODES + 3) / 4, 256, 0, stream>>>(rowptr, colidx, h1, as1, ad1, b1, hout1);
    gemm2_kernel<<<(N_NODES + 255) / 256, 256, 0, stream>>>(hout1, W2, a_src2, a_dst2, h2p, as2, ad2);
    agg2_kernel<<<(N_NODES * 4 + 255) / 256, 256, 0, stream>>>(rowptr, colidx, h2p, as2, ad2, b2, out);
}